// Round 2
// baseline (1691.716 us; speedup 1.0000x reference)
//
#include <hip/hip_runtime.h>
#include <math.h>

#define NLVL  16
#define TSZ   (1u << 19)
#define TMASK (TSZ - 1u)

struct ResArr { int m1[NLVL * 4]; };  // per level, per dim: res-1

// One thread per point. Layer-0 of the MLP is folded into the level loop so
// the h1[64] accumulator replaces the feat[32] array, and the fold of level
// l-1 (128 FMAs off scalar-loaded weights) hides level l's 16 gathers.
// MLP j-loops are fully unrolled: runtime-indexed register arrays would be
// demoted to scratch on gfx950.
__global__ __launch_bounds__(256, 2)
void ingp_fused(const float4* __restrict__ x,
                const float2* __restrict__ table,
                const float*  __restrict__ w0,
                const float*  __restrict__ w1,
                const float*  __restrict__ w2,
                const float*  __restrict__ wout,
                const float*  __restrict__ bout,
                float*        __restrict__ out,
                int N, ResArr res)
{
    const int n = blockIdx.x * blockDim.x + threadIdx.x;
    if (n >= N) return;

    const float4 xv = x[n];
    const float px[4] = {xv.x, xv.y, xv.z, xv.w};

    float h1[64];
    #pragma unroll
    for (int j = 0; j < 64; ++j) h1[j] = 0.0f;

    float a0p = 0.0f, a1p = 0.0f;   // previous level's feature pair

    #pragma unroll 1
    for (int l = 0; l < NLVL; ++l) {
        int   rm[4];
        float fr[4], om[4];
        int   bi[4];
        #pragma unroll
        for (int d = 0; d < 4; ++d) {
            const int r = res.m1[l * 4 + d];          // res-1 (uniform, kernarg)
            rm[d] = r;
            const float pos = px[d] * (float)r;
            const float fb  = floorf(pos);
            fr[d] = pos - fb;
            om[d] = 1.0f - fr[d];
            bi[d] = (int)fb;
        }
        const float2* tl = table + (size_t)l * TSZ;

        float2 fv[16];
        float  wt[16];
        #pragma unroll
        for (int c = 0; c < 16; ++c) {
            int c0 = bi[0] + ( c       & 1);
            int c1 = bi[1] + ((c >> 1) & 1);
            int c2 = bi[2] + ((c >> 2) & 1);
            int c3 = bi[3] + ((c >> 3) & 1);
            c0 = min(max(c0, 0), rm[0]);
            c1 = min(max(c1, 0), rm[1]);
            c2 = min(max(c2, 0), rm[2]);
            c3 = min(max(c3, 0), rm[3]);
            const unsigned hh = (unsigned)c0
                              ^ ((unsigned)c1 * 2654435761u)
                              ^ ((unsigned)c2 * 805459861u)
                              ^ ((unsigned)c3 * 3674653429u);
            fv[c] = tl[hh & TMASK];                    // 8B gather, 16 in flight
            float w = ( c       & 1) ? fr[0] : om[0];
            w      *= ((c >> 1) & 1) ? fr[1] : om[1];
            w      *= ((c >> 2) & 1) ? fr[2] : om[2];
            w      *= ((c >> 3) & 1) ? fr[3] : om[3];
            wt[c] = w;
        }

        // Fold previous level's features into layer-0 accumulators while the
        // 16 gathers are in flight. l==0 folds zeros through w0[0..] (no-op).
        {
            const int lp = (l == 0) ? 0 : (l - 1);
            const float* w0c = w0 + 2 * lp;           // column pair 2*lp, 2*lp+1
            #pragma unroll
            for (int j = 0; j < 64; ++j) {
                h1[j] = fmaf(w0c[j * 32], a0p, fmaf(w0c[j * 32 + 1], a1p, h1[j]));
            }
        }

        float a0 = 0.0f, a1 = 0.0f;
        #pragma unroll
        for (int c = 0; c < 16; ++c) {
            a0 = fmaf(wt[c], fv[c].x, a0);
            a1 = fmaf(wt[c], fv[c].y, a1);
        }
        a0p = a0; a1p = a1;
    }
    {   // final fold (level 15)
        const float* w0c = w0 + 2 * (NLVL - 1);
        #pragma unroll
        for (int j = 0; j < 64; ++j) {
            h1[j] = fmaf(w0c[j * 32], a0p, fmaf(w0c[j * 32 + 1], a1p, h1[j]));
        }
    }
    #pragma unroll
    for (int j = 0; j < 64; ++j) h1[j] = fmaxf(h1[j], 0.0f);

    // Layers 1 and 2: fully unrolled so h1/h2/h3 stay constant-indexed (regs).
    // Weight indices are wave-uniform -> scalar s_load path, zero VALU cost.
    float h2[64];
    #pragma unroll
    for (int j = 0; j < 64; ++j) {
        float acc = 0.0f;
        const float* wr = w1 + j * 64;
        #pragma unroll
        for (int i = 0; i < 64; ++i) acc = fmaf(wr[i], h1[i], acc);
        h2[j] = fmaxf(acc, 0.0f);
    }
    float h3[64];
    #pragma unroll
    for (int j = 0; j < 64; ++j) {
        float acc = 0.0f;
        const float* wr = w2 + j * 64;
        #pragma unroll
        for (int i = 0; i < 64; ++i) acc = fmaf(wr[i], h2[i], acc);
        h3[j] = fmaxf(acc, 0.0f);
    }

    float o[3];
    #pragma unroll
    for (int k = 0; k < 3; ++k) {
        float acc = bout[k];
        const float* wr = wout + k * 64;
        #pragma unroll
        for (int i = 0; i < 64; ++i) acc = fmaf(wr[i], h3[i], acc);
        o[k] = acc;
    }
    out[n * 3 + 0] = o[0];
    out[n * 3 + 1] = o[1];
    out[n * 3 + 2] = o[2];
}

extern "C" void kernel_launch(void* const* d_in, const int* in_sizes, int n_in,
                              void* d_out, int out_size, void* d_ws, size_t ws_size,
                              hipStream_t stream) {
    (void)n_in; (void)d_ws; (void)ws_size; (void)out_size;

    const float* x     = (const float*)d_in[0];
    const float* table = (const float*)d_in[1];
    const float* w0    = (const float*)d_in[2];
    const float* w1    = (const float*)d_in[3];
    const float* w2    = (const float*)d_in[4];
    const float* wout  = (const float*)d_in[5];
    const float* bout  = (const float*)d_in[6];
    float* out = (float*)d_out;

    const int N = in_sizes[0] / 4;

    // Replicate numpy's float64 resolution computation bit-for-bit (same
    // glibc pow). Levels 5/10/15 of dim 3 sit on exact integer boundaries
    // (8^(5/15)==2), so floor() must see the same double as numpy produced.
    ResArr res;
    for (int d = 0; d < 4; ++d) {
        const double minr = 16.0;
        const double maxr = (d == 3) ? 128.0 : 256.0;
        const double growth = pow(maxr / minr, 1.0 / (double)(NLVL - 1));
        for (int l = 0; l < NLVL; ++l) {
            const int r = (int)floor(minr * pow(growth, (double)l));
            res.m1[l * 4 + d] = r - 1;
        }
    }

    dim3 block(256);
    dim3 grid((N + 255) / 256);
    hipLaunchKernelGGL(ingp_fused, grid, block, 0, stream,
                       (const float4*)x, (const float2*)table,
                       w0, w1, w2, wout, bout, out, N, res);
}

// Round 4
// 1285.087 us; speedup vs baseline: 1.3164x; 1.3164x over previous
//
#include <hip/hip_runtime.h>
#include <math.h>

#define NLVL  16
#define TSZ   (1u << 19)
#define TMASK (TSZ - 1u)

struct ResArr { int m1[NLVL * 4]; };  // per level, per dim: res-1

// ---------------------------------------------------------------------------
// Split path kernel 1: hash-grid encode, one (point, level) per thread.
// Grid is LEVEL-MAJOR (blockIdx = level*chunksPerLevel + chunk) so that at any
// instant all XCDs are gathering from the SAME level's 4 MB table, which fits
// each XCD's 4 MB L2 -> line-fill traffic drops from ~5.9 GB (fused, measured
// round 2) to ~1 GB.
// ---------------------------------------------------------------------------
__global__ __launch_bounds__(256, 4)
void ingp_encode(const float4* __restrict__ x,
                 const float2* __restrict__ table,
                 float2*       __restrict__ feat,   // [NLVL][N] level-major
                 int N, int chunksPerLevel, ResArr res)
{
    const int l     = blockIdx.x / chunksPerLevel;
    const int chunk = blockIdx.x - l * chunksPerLevel;
    const int n     = chunk * 256 + threadIdx.x;
    if (n >= N) return;

    const float4 xv = x[n];
    const float px[4] = {xv.x, xv.y, xv.z, xv.w};

    int   rm[4], bi[4];
    float fr[4], om[4];
    #pragma unroll
    for (int d = 0; d < 4; ++d) {
        const int r = res.m1[l * 4 + d];       // wave-uniform -> scalar
        rm[d] = r;
        const float pos = px[d] * (float)r;
        const float fb  = floorf(pos);
        fr[d] = pos - fb;
        om[d] = 1.0f - fr[d];
        bi[d] = (int)fb;
    }
    const float2* tl = table + (size_t)l * TSZ;

    float2 fv[16];
    float  wt[16];
    #pragma unroll
    for (int c = 0; c < 16; ++c) {
        int c0 = bi[0] + ( c       & 1);
        int c1 = bi[1] + ((c >> 1) & 1);
        int c2 = bi[2] + ((c >> 2) & 1);
        int c3 = bi[3] + ((c >> 3) & 1);
        c0 = min(max(c0, 0), rm[0]);
        c1 = min(max(c1, 0), rm[1]);
        c2 = min(max(c2, 0), rm[2]);
        c3 = min(max(c3, 0), rm[3]);
        const unsigned hh = (unsigned)c0
                          ^ ((unsigned)c1 * 2654435761u)
                          ^ ((unsigned)c2 * 805459861u)
                          ^ ((unsigned)c3 * 3674653429u);
        fv[c] = tl[hh & TMASK];
        float w = ( c       & 1) ? fr[0] : om[0];
        w      *= ((c >> 1) & 1) ? fr[1] : om[1];
        w      *= ((c >> 2) & 1) ? fr[2] : om[2];
        w      *= ((c >> 3) & 1) ? fr[3] : om[3];
        wt[c] = w;
    }

    float a0 = 0.0f, a1 = 0.0f;
    #pragma unroll
    for (int c = 0; c < 16; ++c) {           // same order as reference einsum
        a0 = fmaf(wt[c], fv[c].x, a0);
        a1 = fmaf(wt[c], fv[c].y, a1);
    }
    feat[(size_t)l * N + n] = make_float2(a0, a1);
}

// ---------------------------------------------------------------------------
// Split path kernel 2: MLP, one point per thread, fully unrolled (runtime-
// indexed register arrays would demote to scratch). Weight reads are
// wave-uniform -> scalar cache. FMA order identical to the fused round-2
// kernel, which benched absmax == 0.0.
// ---------------------------------------------------------------------------
__global__ __launch_bounds__(256, 2)
void ingp_mlp(const float2* __restrict__ feat,   // [NLVL][N]
              const float*  __restrict__ w0,
              const float*  __restrict__ w1,
              const float*  __restrict__ w2,
              const float*  __restrict__ wout,
              const float*  __restrict__ bout,
              float*        __restrict__ out,
              int N)
{
    const int n = blockIdx.x * blockDim.x + threadIdx.x;
    if (n >= N) return;

    float2 f[NLVL];
    #pragma unroll
    for (int l = 0; l < NLVL; ++l) f[l] = feat[(size_t)l * N + n];  // coalesced

    float h1[64];
    #pragma unroll
    for (int j = 0; j < 64; ++j) h1[j] = 0.0f;
    #pragma unroll
    for (int l = 0; l < NLVL; ++l) {
        #pragma unroll
        for (int j = 0; j < 64; ++j) {
            h1[j] = fmaf(w0[j * 32 + 2 * l], f[l].x,
                    fmaf(w0[j * 32 + 2 * l + 1], f[l].y, h1[j]));
        }
    }
    #pragma unroll
    for (int j = 0; j < 64; ++j) h1[j] = fmaxf(h1[j], 0.0f);

    float h2[64];
    #pragma unroll
    for (int j = 0; j < 64; ++j) {
        float acc = 0.0f;
        const float* wr = w1 + j * 64;
        #pragma unroll
        for (int i = 0; i < 64; ++i) acc = fmaf(wr[i], h1[i], acc);
        h2[j] = fmaxf(acc, 0.0f);
    }
    float h3[64];
    #pragma unroll
    for (int j = 0; j < 64; ++j) {
        float acc = 0.0f;
        const float* wr = w2 + j * 64;
        #pragma unroll
        for (int i = 0; i < 64; ++i) acc = fmaf(wr[i], h2[i], acc);
        h3[j] = fmaxf(acc, 0.0f);
    }
    float o[3];
    #pragma unroll
    for (int k = 0; k < 3; ++k) {
        float acc = bout[k];
        const float* wr = wout + k * 64;
        #pragma unroll
        for (int i = 0; i < 64; ++i) acc = fmaf(wr[i], h3[i], acc);
        o[k] = acc;
    }
    out[n * 3 + 0] = o[0];
    out[n * 3 + 1] = o[1];
    out[n * 3 + 2] = o[2];
}

// ---------------------------------------------------------------------------
// Fallback: round-2 fused kernel (used only if ws is too small for features).
// ---------------------------------------------------------------------------
__global__ __launch_bounds__(256, 2)
void ingp_fused(const float4* __restrict__ x,
                const float2* __restrict__ table,
                const float*  __restrict__ w0,
                const float*  __restrict__ w1,
                const float*  __restrict__ w2,
                const float*  __restrict__ wout,
                const float*  __restrict__ bout,
                float*        __restrict__ out,
                int N, ResArr res)
{
    const int n = blockIdx.x * blockDim.x + threadIdx.x;
    if (n >= N) return;

    const float4 xv = x[n];
    const float px[4] = {xv.x, xv.y, xv.z, xv.w};

    float h1[64];
    #pragma unroll
    for (int j = 0; j < 64; ++j) h1[j] = 0.0f;

    float a0p = 0.0f, a1p = 0.0f;

    #pragma unroll 1
    for (int l = 0; l < NLVL; ++l) {
        int   rm[4], bi[4];
        float fr[4], om[4];
        #pragma unroll
        for (int d = 0; d < 4; ++d) {
            const int r = res.m1[l * 4 + d];
            rm[d] = r;
            const float pos = px[d] * (float)r;
            const float fb  = floorf(pos);
            fr[d] = pos - fb;
            om[d] = 1.0f - fr[d];
            bi[d] = (int)fb;
        }
        const float2* tl = table + (size_t)l * TSZ;

        float2 fv[16];
        float  wt[16];
        #pragma unroll
        for (int c = 0; c < 16; ++c) {
            int c0 = bi[0] + ( c       & 1);
            int c1 = bi[1] + ((c >> 1) & 1);
            int c2 = bi[2] + ((c >> 2) & 1);
            int c3 = bi[3] + ((c >> 3) & 1);
            c0 = min(max(c0, 0), rm[0]);
            c1 = min(max(c1, 0), rm[1]);
            c2 = min(max(c2, 0), rm[2]);
            c3 = min(max(c3, 0), rm[3]);
            const unsigned hh = (unsigned)c0
                              ^ ((unsigned)c1 * 2654435761u)
                              ^ ((unsigned)c2 * 805459861u)
                              ^ ((unsigned)c3 * 3674653429u);
            fv[c] = tl[hh & TMASK];
            float w = ( c       & 1) ? fr[0] : om[0];
            w      *= ((c >> 1) & 1) ? fr[1] : om[1];
            w      *= ((c >> 2) & 1) ? fr[2] : om[2];
            w      *= ((c >> 3) & 1) ? fr[3] : om[3];
            wt[c] = w;
        }
        {
            const int lp = (l == 0) ? 0 : (l - 1);
            const float* w0c = w0 + 2 * lp;
            #pragma unroll
            for (int j = 0; j < 64; ++j)
                h1[j] = fmaf(w0c[j * 32], a0p, fmaf(w0c[j * 32 + 1], a1p, h1[j]));
        }
        float a0 = 0.0f, a1 = 0.0f;
        #pragma unroll
        for (int c = 0; c < 16; ++c) {
            a0 = fmaf(wt[c], fv[c].x, a0);
            a1 = fmaf(wt[c], fv[c].y, a1);
        }
        a0p = a0; a1p = a1;
    }
    {
        const float* w0c = w0 + 2 * (NLVL - 1);
        #pragma unroll
        for (int j = 0; j < 64; ++j)
            h1[j] = fmaf(w0c[j * 32], a0p, fmaf(w0c[j * 32 + 1], a1p, h1[j]));
    }
    #pragma unroll
    for (int j = 0; j < 64; ++j) h1[j] = fmaxf(h1[j], 0.0f);

    float h2[64];
    #pragma unroll
    for (int j = 0; j < 64; ++j) {
        float acc = 0.0f;
        const float* wr = w1 + j * 64;
        #pragma unroll
        for (int i = 0; i < 64; ++i) acc = fmaf(wr[i], h1[i], acc);
        h2[j] = fmaxf(acc, 0.0f);
    }
    float h3[64];
    #pragma unroll
    for (int j = 0; j < 64; ++j) {
        float acc = 0.0f;
        const float* wr = w2 + j * 64;
        #pragma unroll
        for (int i = 0; i < 64; ++i) acc = fmaf(wr[i], h2[i], acc);
        h3[j] = fmaxf(acc, 0.0f);
    }
    float o[3];
    #pragma unroll
    for (int k = 0; k < 3; ++k) {
        float acc = bout[k];
        const float* wr = wout + k * 64;
        #pragma unroll
        for (int i = 0; i < 64; ++i) acc = fmaf(wr[i], h3[i], acc);
        o[k] = acc;
    }
    out[n * 3 + 0] = o[0];
    out[n * 3 + 1] = o[1];
    out[n * 3 + 2] = o[2];
}

extern "C" void kernel_launch(void* const* d_in, const int* in_sizes, int n_in,
                              void* d_out, int out_size, void* d_ws, size_t ws_size,
                              hipStream_t stream) {
    (void)n_in; (void)out_size;

    const float* x     = (const float*)d_in[0];
    const float* table = (const float*)d_in[1];
    const float* w0    = (const float*)d_in[2];
    const float* w1    = (const float*)d_in[3];
    const float* w2    = (const float*)d_in[4];
    const float* wout  = (const float*)d_in[5];
    const float* bout  = (const float*)d_in[6];
    float* out = (float*)d_out;

    const int N = in_sizes[0] / 4;

    // Replicate numpy's float64 resolution computation bit-for-bit (same
    // glibc pow). Levels 5/10/15 of dim 3 sit on exact integer boundaries
    // (8^(5/15)==2), so floor() must see the same double as numpy produced.
    ResArr res;
    for (int d = 0; d < 4; ++d) {
        const double minr = 16.0;
        const double maxr = (d == 3) ? 128.0 : 256.0;
        const double growth = pow(maxr / minr, 1.0 / (double)(NLVL - 1));
        for (int l = 0; l < NLVL; ++l) {
            const int r = (int)floor(minr * pow(growth, (double)l));
            res.m1[l * 4 + d] = r - 1;
        }
    }

    const size_t featBytes = (size_t)NLVL * (size_t)N * sizeof(float2);

    if (ws_size >= featBytes) {
        float2* feat = (float2*)d_ws;
        const int chunksPerLevel = (N + 255) / 256;
        dim3 eg(NLVL * chunksPerLevel), eb(256);
        hipLaunchKernelGGL(ingp_encode, eg, eb, 0, stream,
                           (const float4*)x, (const float2*)table, feat,
                           N, chunksPerLevel, res);
        dim3 mg((N + 255) / 256), mb(256);
        hipLaunchKernelGGL(ingp_mlp, mg, mb, 0, stream,
                           feat, w0, w1, w2, wout, bout, out, N);
    } else {
        dim3 grid((N + 255) / 256), block(256);
        hipLaunchKernelGGL(ingp_fused, grid, block, 0, stream,
                           (const float4*)x, (const float2*)table,
                           w0, w1, w2, wout, bout, out, N, res);
    }
}